// Round 1
// baseline (793.918 us; speedup 1.0000x reference)
//
#include <hip/hip_runtime.h>
#include <cstddef>

#define B_ 64
#define T_ 256
#define C_ 2048
#define H_ 512
#define O_ 11
#define THRESH 1.0f
#define LEAK_ 0.003f
#define OLEAK_ 0.0015f

// ---------------------------------------------------------------------------
// Kernel 1: transpose w_rec (H x H) -> w_recT so the recurrent gather
// (fixed source column h', all dest h) is coalesced.
// ---------------------------------------------------------------------------
__global__ __launch_bounds__(256) void transpose_wrec(const float* __restrict__ w,
                                                      float* __restrict__ wt) {
    __shared__ float tile[32][33];
    int tx = threadIdx.x, ty = threadIdx.y;           // block (32, 8)
    int x = blockIdx.x * 32 + tx;
    int y = blockIdx.y * 32 + ty;
#pragma unroll
    for (int i = 0; i < 32; i += 8)
        tile[ty + i][tx] = w[(size_t)(y + i) * H_ + x];
    __syncthreads();
    int x2 = blockIdx.y * 32 + tx;
    int y2 = blockIdx.x * 32 + ty;
#pragma unroll
    for (int i = 0; i < 32; i += 8)
        wt[(size_t)(y2 + i) * H_ + x2] = tile[tx][ty + i];
}

// ---------------------------------------------------------------------------
// Kernel 2: feedforward GEMM  I1 = X @ w1^T
// X: (M=16384, K=2048) row-major; w1: (N=512, K=2048) row-major (NT gemm).
// 128x128 block tile, BK=16, 256 threads, 8x8 per-thread micro-tile. fp32.
// ---------------------------------------------------------------------------
#define BM 128
#define BN 128
#define BK 16
#define TM 8
#define TN 8

__global__ __launch_bounds__(256) void gemm_ff(const float* __restrict__ A,
                                               const float* __restrict__ Bw,
                                               float* __restrict__ Cmat) {
    const int K = C_;
    const int N = H_;
    __shared__ float As[BK][BM];
    __shared__ float Bs[BK][BN];

    const int t  = threadIdx.x;
    const int tx = t & 15;        // n-dir, 0..15
    const int ty = t >> 4;        // m-dir, 0..15
    const int lr = t >> 2;        // load row 0..63
    const int lc = (t & 3) * 4;   // load col 0,4,8,12

    const float* Aptr = A  + (size_t)(blockIdx.y * BM + lr) * K + lc;
    const float* Bptr = Bw + (size_t)(blockIdx.x * BN + lr) * K + lc;

    float acc[TM][TN];
#pragma unroll
    for (int i = 0; i < TM; ++i)
#pragma unroll
        for (int j = 0; j < TN; ++j) acc[i][j] = 0.f;

    for (int k0 = 0; k0 < K; k0 += BK) {
        float4 a0 = *(const float4*)(Aptr);
        float4 a1 = *(const float4*)(Aptr + (size_t)64 * K);
        float4 b0 = *(const float4*)(Bptr);
        float4 b1 = *(const float4*)(Bptr + (size_t)64 * K);
        Aptr += BK; Bptr += BK;

        __syncthreads();   // previous tile's LDS reads complete
        As[lc + 0][lr] = a0.x; As[lc + 1][lr] = a0.y;
        As[lc + 2][lr] = a0.z; As[lc + 3][lr] = a0.w;
        As[lc + 0][lr + 64] = a1.x; As[lc + 1][lr + 64] = a1.y;
        As[lc + 2][lr + 64] = a1.z; As[lc + 3][lr + 64] = a1.w;
        Bs[lc + 0][lr] = b0.x; Bs[lc + 1][lr] = b0.y;
        Bs[lc + 2][lr] = b0.z; Bs[lc + 3][lr] = b0.w;
        Bs[lc + 0][lr + 64] = b1.x; Bs[lc + 1][lr + 64] = b1.y;
        Bs[lc + 2][lr + 64] = b1.z; Bs[lc + 3][lr + 64] = b1.w;
        __syncthreads();

#pragma unroll
        for (int k = 0; k < BK; ++k) {
            const float4* ap = (const float4*)&As[k][ty * TM];
            const float4* bp = (const float4*)&Bs[k][tx * TN];
            float4 a01 = ap[0], a23 = ap[1];
            float4 b01 = bp[0], b23 = bp[1];
            float av[TM] = {a01.x, a01.y, a01.z, a01.w, a23.x, a23.y, a23.z, a23.w};
            float bv[TN] = {b01.x, b01.y, b01.z, b01.w, b23.x, b23.y, b23.z, b23.w};
#pragma unroll
            for (int i = 0; i < TM; ++i)
#pragma unroll
                for (int j = 0; j < TN; ++j)
                    acc[i][j] += av[i] * bv[j];
        }
    }

    float* Cp = Cmat + (size_t)(blockIdx.y * BM + ty * TM) * N + blockIdx.x * BN + tx * TN;
#pragma unroll
    for (int i = 0; i < TM; ++i) {
        float4 c0 = {acc[i][0], acc[i][1], acc[i][2], acc[i][3]};
        float4 c1 = {acc[i][4], acc[i][5], acc[i][6], acc[i][7]};
        *(float4*)(Cp + (size_t)i * N)     = c0;
        *(float4*)(Cp + (size_t)i * N + 4) = c1;
    }
}

// ---------------------------------------------------------------------------
// Kernel 3: recurrent LIF scan. One block per batch element; 512 threads,
// one hidden neuron per thread. Spikes exchanged via LDS compacted list
// (double-buffered); recurrent current = sparse gather of w_recT columns.
// ---------------------------------------------------------------------------
__global__ __launch_bounds__(512) void snn_rec(const float* __restrict__ I1,
                                               const float* __restrict__ wrT,
                                               const float* __restrict__ w2,
                                               float* __restrict__ out) {
    const int b = blockIdx.x;
    const int h = threadIdx.x;

    __shared__ float w2s[O_ * H_];
    __shared__ int   lists[2][H_];
    __shared__ int   cnts[2];
    __shared__ float v2s[O_];
    __shared__ float osum[O_];

    for (int i = h; i < O_ * H_; i += H_) w2s[i] = w2[i];
    if (h < O_) { v2s[h] = 0.f; osum[h] = 0.f; }
    if (h == 0) { cnts[0] = 0; cnts[1] = 0; }

    float v1 = 0.f;
    const float* i1p = I1 + (size_t)b * T_ * H_ + h;
    __syncthreads();

    for (int t = 0; t < T_; ++t) {
        const int cur  = t & 1;
        const int prev = cur ^ 1;

        // --- recurrent current from previous step's spikes + feedforward ---
        float acc = i1p[(size_t)t * H_] - LEAK_;
        const int  pc = cnts[prev];
        const int* pl = lists[prev];
        int j = 0;
        for (; j + 3 < pc; j += 4) {
            int i0 = pl[j], i1 = pl[j + 1], i2 = pl[j + 2], i3 = pl[j + 3];
            float g0 = wrT[(size_t)i0 * H_ + h];
            float g1 = wrT[(size_t)i1 * H_ + h];
            float g2 = wrT[(size_t)i2 * H_ + h];
            float g3 = wrT[(size_t)i3 * H_ + h];
            acc += g0; acc += g1; acc += g2; acc += g3;
        }
        for (; j < pc; ++j) acc += wrT[(size_t)pl[j] * H_ + h];

        // --- LIF update, subtractive reset ---
        v1 += acc;
        const bool spike = (v1 >= THRESH);
        if (spike) v1 -= THRESH;

        if (h == 0) cnts[cur] = 0;   // safe: last read of cnts[cur] was before t-1's barriers
        __syncthreads();             // B1: cnts[cur] zeroed; prev-list reads done

        if (spike) {
            int idx = atomicAdd(&cnts[cur], 1);
            lists[cur][idx] = h;
        }
        __syncthreads();             // B2: current list complete

        // --- output neuron update (current step's spikes) ---
        if (h < O_) {
            const int  c  = cnts[cur];
            const int* cl = lists[cur];
            float s = 0.f;
            for (int j2 = 0; j2 < c; ++j2) s += w2s[h * H_ + cl[j2]];
            float v2 = v2s[h] + s - OLEAK_;
            v2 = v2 > 0.f ? v2 : 0.f;
            v2s[h] = v2;
            osum[h] += v2;
        }
    }
    __syncthreads();
    if (h < O_) out[b * O_ + h] = osum[h] * (1.0f / (float)T_);
}

// ---------------------------------------------------------------------------
extern "C" void kernel_launch(void* const* d_in, const int* in_sizes, int n_in,
                              void* d_out, int out_size, void* d_ws, size_t ws_size,
                              hipStream_t stream) {
    const float* x     = (const float*)d_in[0];   // (B,T,C)
    const float* w1    = (const float*)d_in[1];   // (H,C)
    const float* w_rec = (const float*)d_in[2];   // (H,H)
    const float* w2    = (const float*)d_in[3];   // (O,H)
    float* out = (float*)d_out;                   // (B,O)

    float* I1  = (float*)d_ws;                                        // 16384*512*4 = 32 MB
    float* wrT = (float*)((char*)d_ws + (size_t)B_ * T_ * H_ * 4);    // +1 MB

    // w_rec transpose
    transpose_wrec<<<dim3(H_ / 32, H_ / 32), dim3(32, 8), 0, stream>>>(w_rec, wrT);

    // feedforward GEMM: I1[(b*T+t), h] = x[b,t,:] . w1[h,:]
    gemm_ff<<<dim3(H_ / BN, (B_ * T_) / BM), dim3(256), 0, stream>>>(x, w1, I1);

    // recurrent scan
    snn_rec<<<dim3(B_), dim3(H_), 0, stream>>>(I1, wrT, w2, out);
}

// Round 2
// 771.681 us; speedup vs baseline: 1.0288x; 1.0288x over previous
//
#include <hip/hip_runtime.h>
#include <cstddef>

#define B_ 64
#define T_ 256
#define C_ 2048
#define H_ 512
#define O_ 11
#define THRESH 1.0f
#define LEAK_ 0.003f
#define OLEAK_ 0.0015f

typedef float v2f __attribute__((ext_vector_type(2)));

// ---------------------------------------------------------------------------
// Kernel 1: transpose w_rec (H x H) -> w_recT (coalesced recurrent gather).
// ---------------------------------------------------------------------------
__global__ __launch_bounds__(256) void transpose_wrec(const float* __restrict__ w,
                                                      float* __restrict__ wt) {
    __shared__ float tile[32][33];
    int tx = threadIdx.x, ty = threadIdx.y;           // block (32, 8)
    int x = blockIdx.x * 32 + tx;
    int y = blockIdx.y * 32 + ty;
#pragma unroll
    for (int i = 0; i < 32; i += 8)
        tile[ty + i][tx] = w[(size_t)(y + i) * H_ + x];
    __syncthreads();
    int x2 = blockIdx.y * 32 + tx;
    int y2 = blockIdx.x * 32 + ty;
#pragma unroll
    for (int i = 0; i < 32; i += 8)
        wt[(size_t)(y2 + i) * H_ + x2] = tile[tx][ty + i];
}

// ---------------------------------------------------------------------------
// Kernel 2: feedforward GEMM  P[s] = X @ w1^T  over K-chunk s (split-K).
// 128x128 tile, BK=16, 256 threads, 8x8 microtile as split 4+4 fragments
// (reads cover contiguous 256B -> bank-conflict-free). float2 accumulation
// so the backend can emit v_pk_fma_f32 (2x fp32 rate).
// ---------------------------------------------------------------------------
#define BM 128
#define BN 128
#define BK 16

template <int S>
__global__ __launch_bounds__(256) void gemm_ff(const float* __restrict__ A,
                                               const float* __restrict__ Bw,
                                               float* __restrict__ Pout) {
    const int K = C_;
    const int N = H_;
    const int kLen  = C_ / S;
    const int kBase = blockIdx.z * kLen;

    __shared__ float As[BK][BM];
    __shared__ float Bs[BK][BN];

    const int t  = threadIdx.x;
    const int tx = t & 15;        // n-dir
    const int ty = t >> 4;        // m-dir
    const int lr = t >> 2;        // load row 0..63
    const int lc = (t & 3) * 4;   // load col 0,4,8,12

    const float* Aptr = A  + (size_t)(blockIdx.y * BM + lr) * K + kBase + lc;
    const float* Bptr = Bw + (size_t)(blockIdx.x * BN + lr) * K + kBase + lc;

    v2f acc[8][4];
#pragma unroll
    for (int i = 0; i < 8; ++i)
#pragma unroll
        for (int j = 0; j < 4; ++j) acc[i][j] = (v2f){0.f, 0.f};

    for (int k0 = 0; k0 < kLen; k0 += BK) {
        float4 a0 = *(const float4*)(Aptr);
        float4 a1 = *(const float4*)(Aptr + (size_t)64 * K);
        float4 b0 = *(const float4*)(Bptr);
        float4 b1 = *(const float4*)(Bptr + (size_t)64 * K);
        Aptr += BK; Bptr += BK;

        __syncthreads();
        As[lc + 0][lr] = a0.x; As[lc + 1][lr] = a0.y;
        As[lc + 2][lr] = a0.z; As[lc + 3][lr] = a0.w;
        As[lc + 0][lr + 64] = a1.x; As[lc + 1][lr + 64] = a1.y;
        As[lc + 2][lr + 64] = a1.z; As[lc + 3][lr + 64] = a1.w;
        Bs[lc + 0][lr] = b0.x; Bs[lc + 1][lr] = b0.y;
        Bs[lc + 2][lr] = b0.z; Bs[lc + 3][lr] = b0.w;
        Bs[lc + 0][lr + 64] = b1.x; Bs[lc + 1][lr + 64] = b1.y;
        Bs[lc + 2][lr + 64] = b1.z; Bs[lc + 3][lr + 64] = b1.w;
        __syncthreads();

#pragma unroll
        for (int k = 0; k < BK; ++k) {
            float4 alo = *(const float4*)&As[k][ty * 4];
            float4 ahi = *(const float4*)&As[k][64 + ty * 4];
            float4 blo = *(const float4*)&Bs[k][tx * 4];
            float4 bhi = *(const float4*)&Bs[k][64 + tx * 4];
            v2f b0v = {blo.x, blo.y}, b1v = {blo.z, blo.w};
            v2f b2v = {bhi.x, bhi.y}, b3v = {bhi.z, bhi.w};
            float av[8] = {alo.x, alo.y, alo.z, alo.w, ahi.x, ahi.y, ahi.z, ahi.w};
#pragma unroll
            for (int i = 0; i < 8; ++i) {
                v2f ai = {av[i], av[i]};
                acc[i][0] += ai * b0v;
                acc[i][1] += ai * b1v;
                acc[i][2] += ai * b2v;
                acc[i][3] += ai * b3v;
            }
        }
    }

    float* P = Pout + (size_t)blockIdx.z * ((size_t)B_ * T_ * H_);
#pragma unroll
    for (int i = 0; i < 8; ++i) {
        int row = blockIdx.y * BM + (i < 4 ? ty * 4 + i : 64 + ty * 4 + (i - 4));
        float* Cp = P + (size_t)row * N + blockIdx.x * BN;
        float4 c0 = {acc[i][0].x, acc[i][0].y, acc[i][1].x, acc[i][1].y};
        float4 c1 = {acc[i][2].x, acc[i][2].y, acc[i][3].x, acc[i][3].y};
        *(float4*)(Cp + tx * 4)      = c0;
        *(float4*)(Cp + 64 + tx * 4) = c1;
    }
}

// ---------------------------------------------------------------------------
// Kernel 3: recurrent LIF scan. One block per batch, 512 threads, 1 neuron
// each. Ballot-compacted spike list (no LDS atomics), unroll-8 gather,
// I1 prefetch, split-K partials summed inline. w2 transposed in LDS.
// ---------------------------------------------------------------------------
template <int S>
__global__ __launch_bounds__(512) void snn_rec(const float* __restrict__ I1,
                                               const float* __restrict__ wrT,
                                               const float* __restrict__ w2,
                                               float* __restrict__ out) {
    const int b    = blockIdx.x;
    const int h    = threadIdx.x;
    const int lane = h & 63;
    const int w    = h >> 6;

    __shared__ float w2sT[H_ * 12];       // [k][o] stride 12 (conflict-free)
    __shared__ int   lists[2][H_];
    __shared__ int   wcnt[8];
    __shared__ float v2s[O_];
    __shared__ float osum[O_];

    // stage w2 transposed: w2sT[k*12+o] = w2[o*H_+k]
    for (int k = h; k < H_; k += H_) {}   // (no-op; keep index simple below)
#pragma unroll
    for (int o = 0; o < O_; ++o) w2sT[h * 12 + o] = w2[o * H_ + h];
    if (h < O_) { v2s[h] = 0.f; osum[h] = 0.f; }

    float v1 = 0.f;
    int   pc = 0;                          // previous step spike count
    const float*  i1p  = I1 + (size_t)b * T_ * H_ + h;
    const float*  wr_h = wrT + h;
    const size_t  PARTF = (size_t)B_ * T_ * H_;

    float pf[S];
#pragma unroll
    for (int s = 0; s < S; ++s) pf[s] = i1p[s * PARTF];   // t=0 prefetch
    __syncthreads();

    for (int t = 0; t < T_; ++t) {
        const int cur = t & 1;

        float acc = -LEAK_;
#pragma unroll
        for (int s = 0; s < S; ++s) acc += pf[s];

        // prefetch next step's feedforward current (hide HBM latency)
        const int tn = (t + 1 < T_) ? t + 1 : t;
#pragma unroll
        for (int s = 0; s < S; ++s) pf[s] = i1p[s * PARTF + (size_t)tn * H_];

        // recurrent gather over previous step's spike list
        const int* pl = lists[cur ^ 1];
        int j = 0;
        for (; j + 7 < pc; j += 8) {
            const int4 ia = *(const int4*)(pl + j);
            const int4 ib = *(const int4*)(pl + j + 4);
            float g0 = wr_h[ia.x * H_];
            float g1 = wr_h[ia.y * H_];
            float g2 = wr_h[ia.z * H_];
            float g3 = wr_h[ia.w * H_];
            float g4 = wr_h[ib.x * H_];
            float g5 = wr_h[ib.y * H_];
            float g6 = wr_h[ib.z * H_];
            float g7 = wr_h[ib.w * H_];
            acc += g0; acc += g1; acc += g2; acc += g3;
            acc += g4; acc += g5; acc += g6; acc += g7;
        }
        for (; j < pc; ++j) acc += wr_h[pl[j] * H_];

        // LIF update, subtractive reset
        v1 += acc;
        const bool spike = (v1 >= THRESH);
        if (spike) v1 -= THRESH;

        // ballot compaction
        unsigned long long m = __ballot(spike);
        int lb = __popcll(m & ((1ull << lane) - 1ull));
        if (lane == 0) wcnt[w] = (int)__popcll(m);
        __syncthreads();                    // B1: wcnt ready

        int base = 0, tot = 0;
#pragma unroll
        for (int ww = 0; ww < 8; ++ww) {
            int c = wcnt[ww];
            if (ww < w) base += c;
            tot += c;
        }
        if (spike) lists[cur][base + lb] = h;
        __syncthreads();                    // B2: list complete

        // output neuron update (11 threads; other waves run ahead to gather)
        if (h < O_) {
            const int* cl = lists[cur];
            float s = 0.f;
            for (int j2 = 0; j2 < tot; ++j2) s += w2sT[cl[j2] * 12 + h];
            float v2 = v2s[h] + s - OLEAK_;
            v2 = v2 > 0.f ? v2 : 0.f;
            v2s[h] = v2;
            osum[h] += v2;
        }
        pc = tot;
    }
    __syncthreads();
    if (h < O_) out[b * O_ + h] = osum[h] * (1.0f / (float)T_);
}

// ---------------------------------------------------------------------------
extern "C" void kernel_launch(void* const* d_in, const int* in_sizes, int n_in,
                              void* d_out, int out_size, void* d_ws, size_t ws_size,
                              hipStream_t stream) {
    const float* x     = (const float*)d_in[0];   // (B,T,C)
    const float* w1    = (const float*)d_in[1];   // (H,C)
    const float* w_rec = (const float*)d_in[2];   // (H,H)
    const float* w2    = (const float*)d_in[3];   // (O,H)
    float* out = (float*)d_out;                   // (B,O)

    const size_t PART = (size_t)B_ * T_ * H_ * sizeof(float);   // 32 MB
    const size_t WRT  = (size_t)H_ * H_ * sizeof(float);        // 1 MB

    int S = 1;
    if (ws_size >= 4 * PART + WRT) S = 4;
    else if (ws_size >= 2 * PART + WRT) S = 2;

    float* P   = (float*)d_ws;
    float* wrT = (float*)((char*)d_ws + (size_t)S * PART);

    transpose_wrec<<<dim3(H_ / 32, H_ / 32), dim3(32, 8), 0, stream>>>(w_rec, wrT);

    dim3 ggrid(H_ / BN, (B_ * T_) / BM, S);
    switch (S) {
        case 4:
            gemm_ff<4><<<ggrid, dim3(256), 0, stream>>>(x, w1, P);
            snn_rec<4><<<dim3(B_), dim3(H_), 0, stream>>>(P, wrT, w2, out);
            break;
        case 2:
            gemm_ff<2><<<ggrid, dim3(256), 0, stream>>>(x, w1, P);
            snn_rec<2><<<dim3(B_), dim3(H_), 0, stream>>>(P, wrT, w2, out);
            break;
        default:
            gemm_ff<1><<<ggrid, dim3(256), 0, stream>>>(x, w1, P);
            snn_rec<1><<<dim3(B_), dim3(H_), 0, stream>>>(P, wrT, w2, out);
            break;
    }
}